// Round 8
// baseline (202.659 us; speedup 1.0000x reference)
//
#include <hip/hip_runtime.h>
#include <cstddef>

// Problem constants (from setup_inputs): B=16, J=1024, L=4096, D=512, fp32.
namespace {
constexpr int Bn = 16;
constexpr int Jn = 1024;
constexpr int Ln = 4096;
constexpr int Dn = 512;
constexpr int G  = 16;          // chunk length along J
constexpr int C  = Jn / G;      // 64 chunks
constexpr float kEps = 1e-4f;
constexpr int PASS1_BLOCKS = Bn * C;  // 1024
}

// clang native vector types — required by __builtin_nontemporal_* (HIP float4
// is a wrapper class the builtin rejects). Same memory layout.
typedef float fvec4 __attribute__((ext_vector_type(4)));
typedef unsigned short usv8 __attribute__((ext_vector_type(8)));

__device__ __forceinline__ unsigned short bf16rne(float x) {
  unsigned u = __float_as_uint(x);
  unsigned r = (u + 0x7fffu + ((u >> 16) & 1u)) >> 16;   // round-to-nearest-even
  return (unsigned short)r;
}
__device__ __forceinline__ float bf16tof(unsigned short h) {
  return __uint_as_float(((unsigned)h) << 16);
}

// --- Kernel 1 (fused): blocks [0,1024): per-(b,chunk) local EMA scan writing
// UNCORRECTED localh[b,j,d] (bf16), chunk-end E (fp32), A-prefix PA/Ap.
// XCD affinity: batch b's blocks run on XCD b/2, matching k_gather's swizzle
// so gather's localh reads hit the same XCD's L2 (write-back, persists).
// Blocks [1024,1040): per-batch boundary cumsum -> gather index idx[b,l].
// R4 lesson: no device-fence last-arriver fusion (per-block L2 writebacks).
__global__ __launch_bounds__(128) void k_fused1(
    const float* __restrict__ emb, const float* __restrict__ conf,
    const int* __restrict__ mask, const int* __restrict__ bnd,
    unsigned short* __restrict__ localh, float* __restrict__ E,
    float* __restrict__ PA, float* __restrict__ Ap, int* __restrict__ idx) {
  int blk = blockIdx.x;
  int t = threadIdx.x;                 // 0..127
  if (blk < PASS1_BLOCKS) {
    int xcd  = blk & 7;
    int slot = blk >> 3;               // 0..127
    int b = 2 * xcd + (slot & 1);      // batches 2x,2x+1 on XCD x
    int c = slot >> 1;                 // 0..63
    int base = b * Jn + c * G;
    fvec4 s = (fvec4)(0.f);
    float prod = 1.0f;
#pragma unroll                          // full unroll: hoist all 16 emb loads
    for (int i = 0; i < G; ++i) {
      int j = base + i;
      float p = conf[j];
      p = fminf(fmaxf(p, kEps), 1.0f - kEps);
      bool m = (mask[j] != 0);
      float q = 1.0f - p;
      fvec4 e = __builtin_nontemporal_load(((const fvec4*)(emb + (size_t)j * Dn)) + t);
      if (m) {
        s = p * e + q * s;
        prod *= q;
      }
      ushort4 h;
      h.x = bf16rne(s.x); h.y = bf16rne(s.y);
      h.z = bf16rne(s.z); h.w = bf16rne(s.w);
      ((ushort4*)(localh + (size_t)j * Dn))[t] = h;   // stays in L2 for gather
      if (t == 0) PA[j] = prod;
    }
    ((fvec4*)(E + ((size_t)(b * C + c)) * Dn))[t] = s;
    if (t == 0) Ap[b * C + c] = prod;
  } else {
    int b = blk - PASS1_BLOCKS;
    const int per = Ln / 128;          // 32 elements per thread
    const int* row = bnd + (size_t)b * Ln;
    int s = 0;
#pragma unroll 8
    for (int i = 0; i < per; ++i) s += (row[t * per + i] != 0) ? 1 : 0;

    __shared__ int sh[128];
    sh[t] = s;
    __syncthreads();
    for (int off = 1; off < 128; off <<= 1) {
      int v = (t >= off) ? sh[t - off] : 0;
      __syncthreads();
      sh[t] += v;
      __syncthreads();
    }
    int run = sh[t] - s;               // exclusive prefix
#pragma unroll 8
    for (int i = 0; i < per; ++i) {
      run += (row[t * per + i] != 0) ? 1 : 0;
      int v = run - 1;
      v = v < 0 ? 0 : (v > Jn - 1 ? Jn - 1 : v);
      idx[(size_t)b * Ln + t * per + i] = v;
    }
  }
}

// --- Kernel 2: cross-chunk recurrence: S[b,c,d] = value entering chunk c.
__global__ __launch_bounds__(64) void k_chunk_start(
    const float* __restrict__ E, const float* __restrict__ Ap,
    float* __restrict__ S) {
  int tg = blockIdx.x * 64 + threadIdx.x;          // over B * D/4 = 2048
  int b = tg / (Dn / 4), d4 = tg % (Dn / 4);
  fvec4 s = (fvec4)(0.f);
#pragma unroll 8
  for (int c = 0; c < C; ++c) {
    ((fvec4*)(S + ((size_t)(b * C + c)) * Dn))[d4] = s;
    float a = Ap[b * C + c];
    fvec4 e = ((const fvec4*)(E + ((size_t)(b * C + c)) * Dn))[d4];
    s = e + a * s;
  }
}

// --- Kernel 3: fused correction + gather upsample, one WAVE per output row.
// frames[b,l,:] = bf16(local[b,j,:]) + PA[b,j] * S[b, j/G, :],  j = idx[b,l].
// 64 lanes x 8 channels = 512 = D: per lane 1x16B localh load, 2x16B S loads,
// 2x16B nt stores — half the instructions/byte of the 2-lane-per-8-floats
// version. Block = 4 waves = 4 consecutive rows. XCD swizzle gives XCD x the
// contiguous row span of batches {2x,2x+1}, matching k_fused1's affinity.
// Out stores nontemporal: 134 MB write-once must not evict localh/S from L2.
__global__ __launch_bounds__(256) void k_gather(
    const unsigned short* __restrict__ localh, const float* __restrict__ PA,
    const float* __restrict__ S, const int* __restrict__ idx,
    float* __restrict__ out) {
  unsigned bid = blockIdx.x;                         // 0..16383
  unsigned sb = (bid & 7u) * 2048u + (bid >> 3);     // bijection on [0,16384)
  int wave = threadIdx.x >> 6;                       // 0..3
  int lane = threadIdx.x & 63;
  size_t r = (size_t)sb * 4 + wave;                  // row = b*L + l, 0..65535
  size_t b = r >> 12;                                // L = 4096
  int j = idx[r];                                    // wave-uniform broadcast
  int c = j >> 4;                                    // chunk of j (G=16)
  float pa = PA[b * Jn + (size_t)j];
  const fvec4* srow = (const fvec4*)(S + (b * C + (size_t)c) * Dn);
  fvec4 s0 = srow[lane * 2 + 0];
  fvec4 s1 = srow[lane * 2 + 1];
  usv8 lh = ((const usv8*)(localh + (b * Jn + (size_t)j) * Dn))[lane];
  fvec4 o0, o1;
  o0.x = bf16tof(lh[0]) + pa * s0.x;
  o0.y = bf16tof(lh[1]) + pa * s0.y;
  o0.z = bf16tof(lh[2]) + pa * s0.z;
  o0.w = bf16tof(lh[3]) + pa * s0.w;
  o1.x = bf16tof(lh[4]) + pa * s1.x;
  o1.y = bf16tof(lh[5]) + pa * s1.y;
  o1.z = bf16tof(lh[6]) + pa * s1.z;
  o1.w = bf16tof(lh[7]) + pa * s1.w;
  fvec4* orow = ((fvec4*)out) + r * (Dn / 4);
  __builtin_nontemporal_store(o0, orow + lane * 2 + 0);
  __builtin_nontemporal_store(o1, orow + lane * 2 + 1);
}

extern "C" void kernel_launch(void* const* d_in, const int* in_sizes, int n_in,
                              void* d_out, int out_size, void* d_ws, size_t ws_size,
                              hipStream_t stream) {
  const float* emb  = (const float*)d_in[0];   // B*J*D fp32
  const float* conf = (const float*)d_in[1];   // B*J fp32
  const int*   mask = (const int*)d_in[2];     // B*J bool -> int
  const int*   bnd  = (const int*)d_in[3];     // B*L bool -> int
  float* out = (float*)d_out;                  // B*L*D fp32

  float* ws = (float*)d_ws;
  unsigned short* localh = (unsigned short*)ws;          // B*J*D bf16 (16.8 MB)
  float* E   = ws + (size_t)Bn * Jn * Dn / 2;            // B*C*D fp32 (2 MB)
  float* S   = E + (size_t)Bn * C * Dn;                  // B*C*D fp32 (2 MB)
  float* PA  = S + (size_t)Bn * C * Dn;                  // B*J
  float* Ap  = PA + (size_t)Bn * Jn;                     // B*C
  int*   idx = (int*)(Ap + Bn * C);                      // B*L

  hipLaunchKernelGGL(k_fused1, dim3(PASS1_BLOCKS + Bn), dim3(128), 0, stream,
                     emb, conf, mask, bnd, localh, E, PA, Ap, idx);
  hipLaunchKernelGGL(k_chunk_start, dim3(Bn * (Dn / 4) / 64), dim3(64), 0, stream,
                     E, Ap, S);
  hipLaunchKernelGGL(k_gather, dim3(Bn * Ln / 4), dim3(256), 0, stream,
                     localh, PA, S, idx, out);
}

// Round 9
// 175.340 us; speedup vs baseline: 1.1558x; 1.1558x over previous
//
#include <hip/hip_runtime.h>
#include <cstddef>

// Problem constants (from setup_inputs): B=16, J=1024, L=4096, D=512, fp32.
namespace {
constexpr int Bn = 16;
constexpr int Jn = 1024;
constexpr int Ln = 4096;
constexpr int Dn = 512;
constexpr int G  = 16;          // chunk length along J
constexpr int C  = Jn / G;      // 64 chunks
constexpr float kEps = 1e-4f;
constexpr int PASS1_BLOCKS = Bn * C;  // 1024
}

// clang native vector types — required by __builtin_nontemporal_* (HIP float4
// is a wrapper class the builtin rejects). Same memory layout.
typedef float fvec4 __attribute__((ext_vector_type(4)));

__device__ __forceinline__ unsigned short bf16rne(float x) {
  unsigned u = __float_as_uint(x);
  unsigned r = (u + 0x7fffu + ((u >> 16) & 1u)) >> 16;   // round-to-nearest-even
  return (unsigned short)r;
}
__device__ __forceinline__ float bf16tof(unsigned short h) {
  return __uint_as_float(((unsigned)h) << 16);
}

// --- Kernel 1 (fused): blocks [0,1024): per-(b,chunk) local EMA scan writing
// UNCORRECTED localh[b,j,d] (bf16), chunk-end E (fp32), A-prefix PA/Ap.
// XCD affinity: batch b's blocks run on XCD b/2, matching k_gather's swizzle
// so gather's localh reads hit the same XCD's L2 (write-back, persists).
// Blocks [1024,1040): per-batch boundary cumsum -> gather index idx[b,l].
// R4 lesson: no device-fence last-arriver fusion (per-block L2 writebacks).
// R8 lesson: keep unroll 8 (full unroll bloats VGPRs) and keep the gather's
// thread-per-float4 layout (lane*2 striding halves store coalescing).
__global__ __launch_bounds__(128) void k_fused1(
    const float* __restrict__ emb, const float* __restrict__ conf,
    const int* __restrict__ mask, const int* __restrict__ bnd,
    unsigned short* __restrict__ localh, float* __restrict__ E,
    float* __restrict__ PA, float* __restrict__ Ap, int* __restrict__ idx) {
  int blk = blockIdx.x;
  int t = threadIdx.x;                 // 0..127
  if (blk < PASS1_BLOCKS) {
    int xcd  = blk & 7;
    int slot = blk >> 3;               // 0..127
    int b = 2 * xcd + (slot & 1);      // batches 2x,2x+1 on XCD x
    int c = slot >> 1;                 // 0..63
    int base = b * Jn + c * G;
    fvec4 s = (fvec4)(0.f);
    float prod = 1.0f;
#pragma unroll 8
    for (int i = 0; i < G; ++i) {
      int j = base + i;
      float p = __builtin_nontemporal_load(conf + j);
      p = fminf(fmaxf(p, kEps), 1.0f - kEps);
      bool m = (__builtin_nontemporal_load(mask + j) != 0);
      float q = 1.0f - p;
      fvec4 e = __builtin_nontemporal_load(((const fvec4*)(emb + (size_t)j * Dn)) + t);
      if (m) {
        s = p * e + q * s;
        prod *= q;
      }
      ushort4 h;
      h.x = bf16rne(s.x); h.y = bf16rne(s.y);
      h.z = bf16rne(s.z); h.w = bf16rne(s.w);
      ((ushort4*)(localh + (size_t)j * Dn))[t] = h;   // stays in L2 for gather
      if (t == 0) PA[j] = prod;
    }
    ((fvec4*)(E + ((size_t)(b * C + c)) * Dn))[t] = s;
    if (t == 0) Ap[b * C + c] = prod;
  } else {
    int b = blk - PASS1_BLOCKS;
    const int per = Ln / 128;          // 32 elements per thread
    const int* row = bnd + (size_t)b * Ln;
    int s = 0;
#pragma unroll 8
    for (int i = 0; i < per; ++i) s += (row[t * per + i] != 0) ? 1 : 0;

    __shared__ int sh[128];
    sh[t] = s;
    __syncthreads();
    for (int off = 1; off < 128; off <<= 1) {
      int v = (t >= off) ? sh[t - off] : 0;
      __syncthreads();
      sh[t] += v;
      __syncthreads();
    }
    int run = sh[t] - s;               // exclusive prefix
#pragma unroll 8
    for (int i = 0; i < per; ++i) {
      run += (row[t * per + i] != 0) ? 1 : 0;
      int v = run - 1;
      v = v < 0 ? 0 : (v > Jn - 1 ? Jn - 1 : v);
      idx[(size_t)b * Ln + t * per + i] = v;
    }
  }
}

// --- Kernel 2: cross-chunk recurrence: S[b,c,d] = value entering chunk c.
__global__ __launch_bounds__(64) void k_chunk_start(
    const float* __restrict__ E, const float* __restrict__ Ap,
    float* __restrict__ S) {
  int tg = blockIdx.x * 64 + threadIdx.x;          // over B * D/4 = 2048
  int b = tg / (Dn / 4), d4 = tg % (Dn / 4);
  fvec4 s = (fvec4)(0.f);
#pragma unroll 8
  for (int c = 0; c < C; ++c) {
    ((fvec4*)(S + ((size_t)(b * C + c)) * Dn))[d4] = s;
    float a = Ap[b * C + c];
    fvec4 e = ((const fvec4*)(E + ((size_t)(b * C + c)) * Dn))[d4];
    s = e + a * s;
  }
}

// --- Kernel 3: fused correction + gather upsample, XCD-swizzled.
// frames[b,l,:] = bf16(local[b,j,:]) + PA[b,j] * S[b, j/G, :],  j = idx[b,l].
// Thread-per-float4: consecutive threads -> consecutive 16B addresses, fully
// coalesced loads and stores (R8 lesson). Swizzle gives XCD x the contiguous
// span = batches {2x,2x+1}, matching k_fused1's affinity so localh reads hit
// the local L2. Out stores nontemporal: write-once 134 MB must not evict
// localh/S from L2.
__global__ __launch_bounds__(256) void k_gather(
    const unsigned short* __restrict__ localh, const float* __restrict__ PA,
    const float* __restrict__ S, const int* __restrict__ idx,
    float* __restrict__ out) {
  unsigned bid = blockIdx.x;                         // 0..32767
  unsigned sb = (bid & 7u) * 4096u + (bid >> 3);     // bijection on [0,32768)
  size_t tid = (size_t)sb * 256 + threadIdx.x;       // over B*L*(D/4)
  int d4 = (int)(tid & (Dn / 4 - 1));                // 0..127
  size_t bl = tid >> 7;                              // b*L + l
  int j = idx[bl];                                   // wave-uniform
  size_t b = bl >> 12;                               // L = 4096
  int c = j >> 4;                                    // chunk of j (G=16)
  float pa = PA[b * Jn + (size_t)j];
  fvec4 sc = ((const fvec4*)(S + (b * C + (size_t)c) * Dn))[d4];
  ushort4 lh = ((const ushort4*)(localh + (b * Jn + (size_t)j) * Dn))[d4];
  fvec4 o;
  o.x = bf16tof(lh.x) + pa * sc.x;
  o.y = bf16tof(lh.y) + pa * sc.y;
  o.z = bf16tof(lh.z) + pa * sc.z;
  o.w = bf16tof(lh.w) + pa * sc.w;
  __builtin_nontemporal_store(o, ((fvec4*)out) + tid);
}

extern "C" void kernel_launch(void* const* d_in, const int* in_sizes, int n_in,
                              void* d_out, int out_size, void* d_ws, size_t ws_size,
                              hipStream_t stream) {
  const float* emb  = (const float*)d_in[0];   // B*J*D fp32
  const float* conf = (const float*)d_in[1];   // B*J fp32
  const int*   mask = (const int*)d_in[2];     // B*J bool -> int
  const int*   bnd  = (const int*)d_in[3];     // B*L bool -> int
  float* out = (float*)d_out;                  // B*L*D fp32

  float* ws = (float*)d_ws;
  unsigned short* localh = (unsigned short*)ws;          // B*J*D bf16 (16.8 MB)
  float* E   = ws + (size_t)Bn * Jn * Dn / 2;            // B*C*D fp32 (2 MB)
  float* S   = E + (size_t)Bn * C * Dn;                  // B*C*D fp32 (2 MB)
  float* PA  = S + (size_t)Bn * C * Dn;                  // B*J
  float* Ap  = PA + (size_t)Bn * Jn;                     // B*C
  int*   idx = (int*)(Ap + Bn * C);                      // B*L

  hipLaunchKernelGGL(k_fused1, dim3(PASS1_BLOCKS + Bn), dim3(128), 0, stream,
                     emb, conf, mask, bnd, localh, E, PA, Ap, idx);
  hipLaunchKernelGGL(k_chunk_start, dim3(Bn * (Dn / 4) / 64), dim3(64), 0, stream,
                     E, Ap, S);
  size_t total4 = (size_t)Bn * Ln * (Dn / 4);
  hipLaunchKernelGGL(k_gather, dim3((unsigned)(total4 / 256)), dim3(256), 0, stream,
                     localh, PA, S, idx, out);
}